// Round 2
// baseline (62.465 us; speedup 1.0000x reference)
//
#include <hip/hip_runtime.h>

#define NAG 128   // num agents
#define TT  100   // timesteps
#define NC  5     // circles per vehicle

// One block per (timestep, scene). Single-pass output: every float4 of the
// scene's g x 128 row-block is written exactly once, coalesced.
//   - out-of-scene column-quads: zero float4 (issued before the LDS barrier)
//   - in-scene column-quads: computed 4-pairs-per-thread, one float4 store
// Scene ranges reproduce searchsorted(ptr[1:], a, 'right') exactly:
//   scene 0    = [0,        ptr[1])
//   scene s    = [ptr[s],   ptr[s+1])  for 1 <= s <= n_ptr-2
//   scene last = [ptr[last], NAG)
__global__ __launch_bounds__(256) void vehcoll_kernel(
    const float* __restrict__ traj,     // (NAG, TT, 4)
    const float* __restrict__ veh_att,  // (NAG, 2)
    const int*   __restrict__ ptr,      // (n_ptr,)
    float* __restrict__ out,            // TT*NAG*NAG penalties + 1 scalar
    int n_ptr)
{
    __shared__ float s_cx[NC][NAG];
    __shared__ float s_cy[NC][NAG];
    __shared__ float s_rad[NAG];

    const int t   = blockIdx.x;
    const int s   = blockIdx.y;
    const int tid = threadIdx.x;

    // ---- num_pairs scalar (last element) ----
    if (t == 0 && s == 0 && tid == 0) {
        int np = 0;
        for (int k = 0; k + 1 < n_ptr; ++k) {
            int gg = ptr[k + 1] - ptr[k];
            np += gg * gg - gg;
        }
        out[(size_t)TT * NAG * NAG] = (float)np;
    }

    // ---- scene row range [a0, a1) ----
    int a0 = (s == 0) ? 0 : ptr[s];
    int a1 = (s == n_ptr - 1) ? NAG : ptr[s + 1];
    a0 = min(max(a0, 0), NAG);
    a1 = min(max(a1, a0), NAG);
    const int g = a1 - a0;
    if (g <= 0) return;

    float* rowbase = out + (size_t)t * NAG * NAG + (size_t)a0 * NAG;
    const float4 z = make_float4(0.f, 0.f, 0.f, 0.f);
    const bool aligned = ((a0 & 3) == 0) && ((g & 3) == 0);

    // ---- zero pass (no LDS dependency -> before the barrier) ----
    if (aligned) {
        const int q0 = a0 >> 2, q1 = a1 >> 2;   // in-scene quad-col range
        const int nq_out = (NAG / 4) - (q1 - q0);
        const int total_out = g * nq_out;
        for (int u = tid; u < total_out; u += 256) {
            const int li = u / nq_out;
            const int k  = u - li * nq_out;
            const int qc = (k < q0) ? k : (k - q0 + q1);
            ((float4*)(rowbase + (size_t)li * NAG))[qc] = z;
        }
    } else {
        // general fallback: zero everything, compute pass overwrites in-scene
        const int nvec = g * (NAG / 4);
        for (int u = tid; u < nvec; u += 256)
            ((float4*)rowbase)[u] = z;
    }

    // ---- stage this scene's circles into LDS ----
    if (tid < g) {
        const int a = a0 + tid;
        float4 tr = *(const float4*)(traj + ((size_t)a * TT + t) * 4);
        float len = veh_att[a * 2 + 0];
        float wid = veh_att[a * 2 + 1];
        float rad  = 0.5f * wid;
        float cmin = rad - 0.5f * len;          // -half_len + rad
        float step = 0.25f * (len - wid);       // (cmax-cmin)/4
        float inv  = 1.0f / sqrtf(tr.z * tr.z + tr.w * tr.w);
        float hx = tr.z * inv, hy = tr.w * inv;
        #pragma unroll
        for (int c = 0; c < NC; ++c) {
            float cx = cmin + step * (float)c;
            s_cx[c][tid] = tr.x + cx * hx;
            s_cy[c][tid] = tr.y + cx * hy;
        }
        s_rad[tid] = rad;
    }
    __syncthreads();

    // ---- compute pass: dense g x g intra-scene pairs ----
    if (aligned) {
        const int nqc = g >> 2;                 // in-scene quads per row
        const int total_c = g * nqc;
        for (int u = tid; u < total_c; u += 256) {
            const int li = u / nqc;
            const int k  = u - li * nqc;
            float ixr[NC], iyr[NC];
            #pragma unroll
            for (int c = 0; c < NC; ++c) { ixr[c] = s_cx[c][li]; iyr[c] = s_cy[c][li]; }
            const float ri = s_rad[li];
            float pen[4];
            #pragma unroll
            for (int q = 0; q < 4; ++q) {
                const int lj = k * 4 + q;
                float minsq = 3.4e38f;
                #pragma unroll
                for (int ci = 0; ci < NC; ++ci)
                    #pragma unroll
                    for (int cj = 0; cj < NC; ++cj) {
                        float dx = ixr[ci] - s_cx[cj][lj];
                        float dy = iyr[ci] - s_cy[cj][lj];
                        minsq = fminf(minsq, dx * dx + dy * dy);
                    }
                float d  = sqrtf(minsq);        // min dist == sqrt(min sq)
                float pd = ri + s_rad[lj];      // BUFFER_DIST = 0
                pen[q] = (li != lj && d <= pd) ? 1.0f - d / pd : 0.0f;
            }
            ((float4*)(rowbase + (size_t)li * NAG + a0))[k] =
                make_float4(pen[0], pen[1], pen[2], pen[3]);
        }
    } else {
        const int npair = g * g;
        for (int p = tid; p < npair; p += 256) {
            const int li = p / g;
            const int lj = p - li * g;
            if (li == lj) continue;             // diagonal stays zero
            float minsq = 3.4e38f;
            #pragma unroll
            for (int ci = 0; ci < NC; ++ci)
                #pragma unroll
                for (int cj = 0; cj < NC; ++cj) {
                    float dx = s_cx[ci][li] - s_cx[cj][lj];
                    float dy = s_cy[ci][li] - s_cy[cj][lj];
                    minsq = fminf(minsq, dx * dx + dy * dy);
                }
            float d  = sqrtf(minsq);
            float pd = s_rad[li] + s_rad[lj];
            float pen = (d <= pd) ? 1.0f - d / pd : 0.0f;
            rowbase[(size_t)li * NAG + a0 + lj] = pen;
        }
    }
}

extern "C" void kernel_launch(void* const* d_in, const int* in_sizes, int n_in,
                              void* d_out, int out_size, void* d_ws, size_t ws_size,
                              hipStream_t stream) {
    const float* traj    = (const float*)d_in[0];
    const float* veh_att = (const float*)d_in[1];
    const int*   ptr     = (const int*)d_in[2];
    float*       out     = (float*)d_out;
    const int n_ptr = in_sizes[2];

    dim3 grid(TT, n_ptr > 0 ? n_ptr : 1);
    dim3 block(256);
    hipLaunchKernelGGL(vehcoll_kernel, grid, block, 0, stream,
                       traj, veh_att, ptr, out, n_ptr);
}